// Round 9
// baseline (72.504 us; speedup 1.0000x reference)
//
#include <hip/hip_runtime.h>
#include <hip/hip_bf16.h>

#define D_MODEL 1024
#define HEAD 64
#define TSEQ 2048
#define NB 4
#define BT (NB * TSEQ)

typedef __bf16 bf16x8 __attribute__((ext_vector_type(8)));
typedef __bf16 bf16x4 __attribute__((ext_vector_type(4)));
typedef float f32x4 __attribute__((ext_vector_type(4)));

#define LOG2E 1.44269504088896f

__device__ inline unsigned pkbf(float a, float b) {
    union { __bf16 h[2]; unsigned u; } t;
    t.h[0] = (__bf16)a; t.h[1] = (__bf16)b;
    return t.u;
}

// ---------------------------------------------------------------------------
// Kernel 0: W transpose + bf16 convert. wt[(tsel*64+col)*1024 + k] = W[k][col]
// (unchanged)
// ---------------------------------------------------------------------------
__global__ __launch_bounds__(256) void wt_kernel(
    const float* __restrict__ Wq, const float* __restrict__ Wk,
    const float* __restrict__ Wv, __bf16* __restrict__ wt)
{
    __shared__ float tile[64][65];
    int tsel = blockIdx.x >> 4;
    int k0 = (blockIdx.x & 15) * 64;
    const float* W = tsel == 0 ? Wq : (tsel == 1 ? Wk : Wv);
    int tid = threadIdx.x;
#pragma unroll
    for (int i = 0; i < 16; ++i) {
        int idx = i * 256 + tid;
        int k = idx >> 6, c = idx & 63;
        tile[k][c] = W[(size_t)(k0 + k) * 64 + c];
    }
    __syncthreads();
#pragma unroll
    for (int i = 0; i < 16; ++i) {
        int idx = i * 256 + tid;
        int c = idx >> 6, k = idx & 63;
        wt[(size_t)(tsel * 64 + c) * 1024 + k0 + k] = (__bf16)tile[k][c];
    }
}

// ---------------------------------------------------------------------------
// Kernel 1: QKV MFMA GEMM, 8 waves = 4-way K-split x 2-way col-split.
// ROUND 9: all 16 x-loads (this wave's whole 64-f32/lane footprint) issued
// UPFRONT -> 16 outstanding HBM loads per wave instead of prefetch depth 1.
// The 8-step MFMA loop then drains them with descending vmcnt while wt
// (L2-resident) loads stay in-loop. LDS reduce epilogue unchanged.
// ---------------------------------------------------------------------------
__global__ __launch_bounds__(512) void qkv_gemm(
    const float* __restrict__ x, const __bf16* __restrict__ wt,
    const float* __restrict__ bq, const float* __restrict__ bk, const float* __restrict__ bv,
    __bf16* __restrict__ qs, __bf16* __restrict__ ks, __bf16* __restrict__ vT)
{
    __shared__ f32x4 red[8][6][64];   // 48 KB [wave][coltile][lane]

    int r0 = blockIdx.x * 16;
    int tid = threadIdx.x;
    int w = tid >> 6;                 // 0..7
    int kq = w >> 1;                  // K quarter
    int ch = w & 1;                   // column half (96 cols)
    int lane = tid & 63;
    int c16 = lane & 15, g = lane >> 4;

    const float* xbase = x + (size_t)(r0 + c16) * D_MODEL + kq * 256 + g * 8;

    // ---- issue ALL x loads upfront: 16 dwordx4 in flight per lane ----
    float4 xr[16];
#pragma unroll
    for (int i = 0; i < 16; ++i)
        xr[i] = *(const float4*)(xbase + (i >> 1) * 32 + (i & 1) * 4);

    f32x4 acc[6];
#pragma unroll
    for (int j = 0; j < 6; ++j) acc[j] = (f32x4){0.f, 0.f, 0.f, 0.f};

    const __bf16* wbase = wt + (size_t)(ch * 96 + c16) * D_MODEL + kq * 256 + g * 8;

#pragma unroll
    for (int kt = 0; kt < 8; ++kt) {
        float4 xa = xr[2 * kt], xb = xr[2 * kt + 1];
        bf16x8 af;
        af[0] = (__bf16)xa.x; af[1] = (__bf16)xa.y;
        af[2] = (__bf16)xa.z; af[3] = (__bf16)xa.w;
        af[4] = (__bf16)xb.x; af[5] = (__bf16)xb.y;
        af[6] = (__bf16)xb.z; af[7] = (__bf16)xb.w;

        const __bf16* wk = wbase + kt * 32;
#pragma unroll
        for (int j = 0; j < 6; ++j) {
            bf16x8 bfr = *(const bf16x8*)(wk + (size_t)j * 16 * D_MODEL);
            acc[j] = __builtin_amdgcn_mfma_f32_16x16x32_bf16(af, bfr, acc[j], 0, 0, 0);
        }
    }

#pragma unroll
    for (int j = 0; j < 6; ++j) red[w][j][lane] = acc[j];
    __syncthreads();

#pragma unroll
    for (int pass = 0; pass < 2; ++pass) {
        if (pass == 1 && w >= 4) break;
        int jt = (pass == 0) ? w : 8 + w;
        int chh = jt / 6, j = jt % 6;
        f32x4 s = red[0 + chh][j][lane] + red[2 + chh][j][lane]
                + red[4 + chh][j][lane] + red[6 + chh][j][lane];
        int tsel = jt >> 2;               // 0=q 1=k 2=v
        int cm = (jt & 3) * 16 + c16;     // column within its 64-col matrix
        const float* bias = tsel == 0 ? bq : (tsel == 1 ? bk : bv);
        float bval = bias[cm];
        if (tsel == 0) {
            // q pre-scaled by 1/sqrt(1024) * log2(e) so attn can use exp2
#pragma unroll
            for (int r = 0; r < 4; ++r)
                qs[(size_t)(r0 + g * 4 + r) * HEAD + cm] = (__bf16)((s[r] + bval) * (0.03125f * LOG2E));
        } else if (tsel == 1) {
#pragma unroll
            for (int r = 0; r < 4; ++r)
                ks[(size_t)(r0 + g * 4 + r) * HEAD + cm] = (__bf16)(s[r] + bval);
        } else {
#pragma unroll
            for (int r = 0; r < 4; ++r) {
                int row = r0 + g * 4 + r;
                int b = row >> 11, t = row & (TSEQ - 1);
                vT[(size_t)(b * HEAD + cm) * TSEQ + t] = (__bf16)(s[r] + bval);
            }
        }
    }
}

// ---------------------------------------------------------------------------
// Kernel 2: flash attention, 8-way key-split, swapped QK^T (unchanged, R8).
// ---------------------------------------------------------------------------
__global__ __launch_bounds__(512) void attn_mfma(
    const __bf16* __restrict__ qs, const __bf16* __restrict__ ks,
    const __bf16* __restrict__ vT, float* __restrict__ out)
{
    __shared__ __align__(16) f32x4 ocomb[8][4][64];     // 32 KB [wave][hh][lane]
    __shared__ float mcomb[8][16];                      // [wave][qrow]
    __shared__ float lcomb[8][16];

    int blk = blockIdx.x;
    int b = blk >> 7;
    int qt = 127 - (blk & 127);         // heavy q-tiles first
    int qb = qt * 16;

    int tid = threadIdx.x;
    int w = tid >> 6;                   // 0..7
    int lane = tid & 63;
    int g = lane >> 4;
    int c16 = lane & 15;

    const __bf16* qsb = qs + (size_t)(b * TSEQ + qb) * HEAD;
    const __bf16* kb_ = ks + (size_t)b * TSEQ * HEAD;
    const __bf16* vb_ = vT + (size_t)b * HEAD * TSEQ;

    bf16x8 qf0 = *(const bf16x8*)(qsb + c16 * HEAD + g * 8);
    bf16x8 qf1 = *(const bf16x8*)(qsb + c16 * HEAD + 32 + g * 8);

    f32x4 o0 = {0.f, 0.f, 0.f, 0.f}, o1 = o0, o2 = o0, o3 = o0;
    float m = -3.0e38f, l = 0.f;

    int nt = (qb + 47) >> 5;            // number of 32-key tiles
    int qrow = qb + c16;

    for (int ti = w; ti < nt; ti += 8) {
        int kbase = ti * 32;

        // ---- QK^T (swapped: K as A, Q as B -> S^T) ----
        const __bf16* kr0 = kb_ + (size_t)(kbase + c16) * HEAD + g * 8;
        bf16x8 k00 = *(const bf16x8*)(kr0);
        bf16x8 k01 = *(const bf16x8*)(kr0 + 32);
        const __bf16* kr1 = kr0 + 16 * HEAD;
        bf16x8 k10 = *(const bf16x8*)(kr1);
        bf16x8 k11 = *(const bf16x8*)(kr1 + 32);

        f32x4 z = {0.f, 0.f, 0.f, 0.f};
        f32x4 s0 = __builtin_amdgcn_mfma_f32_16x16x32_bf16(k00, qf0, z, 0, 0, 0);
        s0 = __builtin_amdgcn_mfma_f32_16x16x32_bf16(k01, qf1, s0, 0, 0, 0);
        f32x4 s1 = __builtin_amdgcn_mfma_f32_16x16x32_bf16(k10, qf0, z, 0, 0, 0);
        s1 = __builtin_amdgcn_mfma_f32_16x16x32_bf16(k11, qf1, s1, 0, 0, 0);

        // ---- causal mask (keys are in-lane) ----
        if (kbase + 31 > qb) {
#pragma unroll
            for (int r = 0; r < 4; ++r) {
                if (kbase + 4 * g + r > qrow)      s0[r] = -3.0e38f;
                if (kbase + 16 + 4 * g + r > qrow) s1[r] = -3.0e38f;
            }
        }

        // ---- online softmax: lane-local row ----
        float vmax = fmaxf(fmaxf(fmaxf(s0[0], s0[1]), fmaxf(s0[2], s0[3])),
                           fmaxf(fmaxf(s1[0], s1[1]), fmaxf(s1[2], s1[3])));
        vmax = fmaxf(vmax, __shfl_xor(vmax, 16, 64));
        vmax = fmaxf(vmax, __shfl_xor(vmax, 32, 64));
        float mn = fmaxf(m, vmax);
        float al = exp2f(m - mn);
        m = mn;

        float p0[4], p1[4];
        float rsum = 0.f;
#pragma unroll
        for (int r = 0; r < 4; ++r) {
            p0[r] = exp2f(s0[r] - m);
            p1[r] = exp2f(s1[r] - m);
            rsum += p0[r] + p1[r];
        }
        rsum += __shfl_xor(rsum, 16, 64);
        rsum += __shfl_xor(rsum, 32, 64);
        l = l * al + rsum;
        o0 *= al; o1 *= al; o2 *= al; o3 *= al;

        // ---- P^T redistribution: pack bf16 pairs, 8 shfl ----
        unsigned pk[4];
        pk[0] = pkbf(p0[0], p0[1]); pk[1] = pkbf(p0[2], p0[3]);
        pk[2] = pkbf(p1[0], p1[1]); pk[3] = pkbf(p1[2], p1[3]);

        union { unsigned u[4]; bf16x8 v; } pb;
#pragma unroll
        for (int t = 0; t < 4; ++t) {
            int srcl = c16 + 16 * ((2 * g + (t >> 1)) & 3);
            unsigned lo = (unsigned)__shfl((int)pk[t & 1], srcl, 64);
            unsigned hi = (unsigned)__shfl((int)pk[2 + (t & 1)], srcl, 64);
            pb.u[t] = (g < 2) ? lo : hi;
        }

        // ---- PV: O^T += V^T x P^T (V as A-operand) ----
        const __bf16* vbase = vb_ + kbase + g * 8;
        o0 = __builtin_amdgcn_mfma_f32_16x16x32_bf16(*(const bf16x8*)(vbase + (size_t)(c16) * TSEQ), pb.v, o0, 0, 0, 0);
        o1 = __builtin_amdgcn_mfma_f32_16x16x32_bf16(*(const bf16x8*)(vbase + (size_t)(c16 + 16) * TSEQ), pb.v, o1, 0, 0, 0);
        o2 = __builtin_amdgcn_mfma_f32_16x16x32_bf16(*(const bf16x8*)(vbase + (size_t)(c16 + 32) * TSEQ), pb.v, o2, 0, 0, 0);
        o3 = __builtin_amdgcn_mfma_f32_16x16x32_bf16(*(const bf16x8*)(vbase + (size_t)(c16 + 48) * TSEQ), pb.v, o3, 0, 0, 0);
    }

    // ---- publish partials ----
    ocomb[w][0][lane] = o0;
    ocomb[w][1][lane] = o1;
    ocomb[w][2][lane] = o2;
    ocomb[w][3][lane] = o3;
    if (g == 0) {
        mcomb[w][c16] = m;
        lcomb[w][c16] = l;
    }
    __syncthreads();

    // ---- combine: wave w<4 finalizes h-tile hh=w ----
    if (w < 4) {
        float M = mcomb[0][c16];
#pragma unroll
        for (int sw = 1; sw < 8; ++sw) M = fmaxf(M, mcomb[sw][c16]);
        f32x4 O = {0.f, 0.f, 0.f, 0.f};
        float L = 0.f;
#pragma unroll
        for (int sw = 0; sw < 8; ++sw) {
            float e = exp2f(mcomb[sw][c16] - M);
            L += lcomb[sw][c16] * e;
            f32x4 po = ocomb[sw][w][lane];
            O[0] += po[0] * e; O[1] += po[1] * e;
            O[2] += po[2] * e; O[3] += po[3] * e;
        }
        float rcp = 1.0f / L;
        f32x4 res = {O[0] * rcp, O[1] * rcp, O[2] * rcp, O[3] * rcp};
        *(f32x4*)(out + (size_t)(b * TSEQ + qb + c16) * HEAD + w * 16 + g * 4) = res;
    }
}

extern "C" void kernel_launch(void* const* d_in, const int* in_sizes, int n_in,
                              void* d_out, int out_size, void* d_ws, size_t ws_size,
                              hipStream_t stream) {
    const float* x  = (const float*)d_in[0];
    const float* Wk = (const float*)d_in[1];
    const float* Wq = (const float*)d_in[2];
    const float* Wv = (const float*)d_in[3];
    const float* bk = (const float*)d_in[4];
    const float* bq = (const float*)d_in[5];
    const float* bv = (const float*)d_in[6];
    float* out = (float*)d_out;

    __bf16* qs = (__bf16*)d_ws;                        // [BT][64]        1 MB
    __bf16* ks = qs + (size_t)BT * HEAD;               // [BT][64]        1 MB
    __bf16* vT = ks + (size_t)BT * HEAD;               // [NB][64][TSEQ]  1 MB
    __bf16* wt = vT + (size_t)BT * HEAD;               // [192][1024]     384 KB

    wt_kernel<<<48, 256, 0, stream>>>(Wq, Wk, Wv, wt);
    qkv_gemm<<<BT / 16, 512, 0, stream>>>(x, wt, bq, bk, bv, qs, ks, vT);
    attn_mfma<<<512, 512, 0, stream>>>(qs, ks, vT, out);
}

// Round 10
// 65.015 us; speedup vs baseline: 1.1152x; 1.1152x over previous
//
#include <hip/hip_runtime.h>
#include <hip/hip_bf16.h>

#define D_MODEL 1024
#define HEAD 64
#define TSEQ 2048
#define NB 4
#define BT (NB * TSEQ)

typedef __bf16 bf16x8 __attribute__((ext_vector_type(8)));
typedef __bf16 bf16x4 __attribute__((ext_vector_type(4)));
typedef float f32x4 __attribute__((ext_vector_type(4)));

#define LOG2E 1.44269504088896f

__device__ inline unsigned pkbf(float a, float b) {
    union { __bf16 h[2]; unsigned u; } t;
    t.h[0] = (__bf16)a; t.h[1] = (__bf16)b;
    return t.u;
}

// ---------------------------------------------------------------------------
// Kernel 0: W transpose + bf16 convert. wt[(tsel*64+col)*1024 + k] = W[k][col]
// (unchanged)
// ---------------------------------------------------------------------------
__global__ __launch_bounds__(256) void wt_kernel(
    const float* __restrict__ Wq, const float* __restrict__ Wk,
    const float* __restrict__ Wv, __bf16* __restrict__ wt)
{
    __shared__ float tile[64][65];
    int tsel = blockIdx.x >> 4;
    int k0 = (blockIdx.x & 15) * 64;
    const float* W = tsel == 0 ? Wq : (tsel == 1 ? Wk : Wv);
    int tid = threadIdx.x;
#pragma unroll
    for (int i = 0; i < 16; ++i) {
        int idx = i * 256 + tid;
        int k = idx >> 6, c = idx & 63;
        tile[k][c] = W[(size_t)(k0 + k) * 64 + c];
    }
    __syncthreads();
#pragma unroll
    for (int i = 0; i < 16; ++i) {
        int idx = i * 256 + tid;
        int c = idx >> 6, k = idx & 63;
        wt[(size_t)(tsel * 64 + c) * 1024 + k0 + k] = (__bf16)tile[k][c];
    }
}

// ---------------------------------------------------------------------------
// Kernel 1: QKV MFMA GEMM, 8 waves = 4-way K-split x 2-way col-split.
// ROUND 10: XCD-chunked blockIdx swizzle (T1). MI355X CP assigns workgroup
// d to XCD d%8; remapping strip = (d%8)*64 + d/8 gives XCD i the contiguous
// row range [i*1024, (i+1)*1024) -> its x slice is 4 MB = one L2, and wt
// (384 KB) becomes XCD-resident after warmup. Internals = round 7 (depth-1
// prefetch; xr[16] reverted to keep VGPR/occupancy).
// ---------------------------------------------------------------------------
__global__ __launch_bounds__(512) void qkv_gemm(
    const float* __restrict__ x, const __bf16* __restrict__ wt,
    const float* __restrict__ bq, const float* __restrict__ bk, const float* __restrict__ bv,
    __bf16* __restrict__ qs, __bf16* __restrict__ ks, __bf16* __restrict__ vT)
{
    __shared__ f32x4 red[8][6][64];   // 48 KB [wave][coltile][lane]

    int d = blockIdx.x;
    int strip = (d & 7) * 64 + (d >> 3);   // XCD-chunked swizzle (512 = 8*64)
    int r0 = strip * 16;
    int tid = threadIdx.x;
    int w = tid >> 6;                 // 0..7
    int kq = w >> 1;                  // K quarter
    int ch = w & 1;                   // column half (96 cols)
    int lane = tid & 63;
    int c16 = lane & 15, g = lane >> 4;

    f32x4 acc[6];
#pragma unroll
    for (int j = 0; j < 6; ++j) acc[j] = (f32x4){0.f, 0.f, 0.f, 0.f};

    const float* xbase = x + (size_t)(r0 + c16) * D_MODEL + kq * 256 + g * 8;
    const __bf16* wbase = wt + (size_t)(ch * 96 + c16) * D_MODEL + kq * 256 + g * 8;

    float4 xa = *(const float4*)(xbase);
    float4 xb = *(const float4*)(xbase + 4);

#pragma unroll
    for (int kt = 0; kt < 8; ++kt) {
        int k0 = kt * 32;
        float4 xa_n, xb_n;
        if (kt < 7) {                              // rolling prefetch
            xa_n = *(const float4*)(xbase + k0 + 32);
            xb_n = *(const float4*)(xbase + k0 + 36);
        }
        bf16x8 af;
        af[0] = (__bf16)xa.x; af[1] = (__bf16)xa.y;
        af[2] = (__bf16)xa.z; af[3] = (__bf16)xa.w;
        af[4] = (__bf16)xb.x; af[5] = (__bf16)xb.y;
        af[6] = (__bf16)xb.z; af[7] = (__bf16)xb.w;

        const __bf16* wk = wbase + k0;
#pragma unroll
        for (int j = 0; j < 6; ++j) {
            bf16x8 bfr = *(const bf16x8*)(wk + (size_t)j * 16 * D_MODEL);
            acc[j] = __builtin_amdgcn_mfma_f32_16x16x32_bf16(af, bfr, acc[j], 0, 0, 0);
        }
        xa = xa_n; xb = xb_n;
    }

#pragma unroll
    for (int j = 0; j < 6; ++j) red[w][j][lane] = acc[j];
    __syncthreads();

#pragma unroll
    for (int pass = 0; pass < 2; ++pass) {
        if (pass == 1 && w >= 4) break;
        int jt = (pass == 0) ? w : 8 + w;
        int chh = jt / 6, j = jt % 6;
        f32x4 s = red[0 + chh][j][lane] + red[2 + chh][j][lane]
                + red[4 + chh][j][lane] + red[6 + chh][j][lane];
        int tsel = jt >> 2;               // 0=q 1=k 2=v
        int cm = (jt & 3) * 16 + c16;     // column within its 64-col matrix
        const float* bias = tsel == 0 ? bq : (tsel == 1 ? bk : bv);
        float bval = bias[cm];
        if (tsel == 0) {
            // q pre-scaled by 1/sqrt(1024) * log2(e) so attn can use exp2
#pragma unroll
            for (int r = 0; r < 4; ++r)
                qs[(size_t)(r0 + g * 4 + r) * HEAD + cm] = (__bf16)((s[r] + bval) * (0.03125f * LOG2E));
        } else if (tsel == 1) {
#pragma unroll
            for (int r = 0; r < 4; ++r)
                ks[(size_t)(r0 + g * 4 + r) * HEAD + cm] = (__bf16)(s[r] + bval);
        } else {
#pragma unroll
            for (int r = 0; r < 4; ++r) {
                int row = r0 + g * 4 + r;
                int b = row >> 11, t = row & (TSEQ - 1);
                vT[(size_t)(b * HEAD + cm) * TSEQ + t] = (__bf16)(s[r] + bval);
            }
        }
    }
}

// ---------------------------------------------------------------------------
// Kernel 2: flash attention, 8-way key-split, swapped QK^T (R8 internals).
// ROUND 10: XCD swizzle — XCD pair (2b,2b+1) owns batch b (its K+V = 512 KB
// fits one L2, and qkv wrote that batch's K/V from the same XCDs). qt
// interleaved by parity for balance, heavy-first within each XCD.
//   d%8 = xcd; slot = d/8;  b = xcd>>1; p = xcd&1; qt = (p?127:126) - 2*slot
// ---------------------------------------------------------------------------
__global__ __launch_bounds__(512) void attn_mfma(
    const __bf16* __restrict__ qs, const __bf16* __restrict__ ks,
    const __bf16* __restrict__ vT, float* __restrict__ out)
{
    __shared__ __align__(16) f32x4 ocomb[8][4][64];     // 32 KB [wave][hh][lane]
    __shared__ float mcomb[8][16];                      // [wave][qrow]
    __shared__ float lcomb[8][16];

    int d = blockIdx.x;
    int xcd = d & 7;
    int slot = d >> 3;                  // 0..63
    int b = xcd >> 1;
    int qt = ((xcd & 1) ? 127 : 126) - 2 * slot;   // heavy-first, parity split
    int qb = qt * 16;

    int tid = threadIdx.x;
    int w = tid >> 6;                   // 0..7
    int lane = tid & 63;
    int g = lane >> 4;
    int c16 = lane & 15;

    const __bf16* qsb = qs + (size_t)(b * TSEQ + qb) * HEAD;
    const __bf16* kb_ = ks + (size_t)b * TSEQ * HEAD;
    const __bf16* vb_ = vT + (size_t)b * HEAD * TSEQ;

    bf16x8 qf0 = *(const bf16x8*)(qsb + c16 * HEAD + g * 8);
    bf16x8 qf1 = *(const bf16x8*)(qsb + c16 * HEAD + 32 + g * 8);

    f32x4 o0 = {0.f, 0.f, 0.f, 0.f}, o1 = o0, o2 = o0, o3 = o0;
    float m = -3.0e38f, l = 0.f;

    int nt = (qb + 47) >> 5;            // number of 32-key tiles
    int qrow = qb + c16;

    for (int ti = w; ti < nt; ti += 8) {
        int kbase = ti * 32;

        // ---- QK^T (swapped: K as A, Q as B -> S^T) ----
        const __bf16* kr0 = kb_ + (size_t)(kbase + c16) * HEAD + g * 8;
        bf16x8 k00 = *(const bf16x8*)(kr0);
        bf16x8 k01 = *(const bf16x8*)(kr0 + 32);
        const __bf16* kr1 = kr0 + 16 * HEAD;
        bf16x8 k10 = *(const bf16x8*)(kr1);
        bf16x8 k11 = *(const bf16x8*)(kr1 + 32);

        f32x4 z = {0.f, 0.f, 0.f, 0.f};
        f32x4 s0 = __builtin_amdgcn_mfma_f32_16x16x32_bf16(k00, qf0, z, 0, 0, 0);
        s0 = __builtin_amdgcn_mfma_f32_16x16x32_bf16(k01, qf1, s0, 0, 0, 0);
        f32x4 s1 = __builtin_amdgcn_mfma_f32_16x16x32_bf16(k10, qf0, z, 0, 0, 0);
        s1 = __builtin_amdgcn_mfma_f32_16x16x32_bf16(k11, qf1, s1, 0, 0, 0);

        // ---- causal mask (keys are in-lane) ----
        if (kbase + 31 > qb) {
#pragma unroll
            for (int r = 0; r < 4; ++r) {
                if (kbase + 4 * g + r > qrow)      s0[r] = -3.0e38f;
                if (kbase + 16 + 4 * g + r > qrow) s1[r] = -3.0e38f;
            }
        }

        // ---- online softmax: lane-local row ----
        float vmax = fmaxf(fmaxf(fmaxf(s0[0], s0[1]), fmaxf(s0[2], s0[3])),
                           fmaxf(fmaxf(s1[0], s1[1]), fmaxf(s1[2], s1[3])));
        vmax = fmaxf(vmax, __shfl_xor(vmax, 16, 64));
        vmax = fmaxf(vmax, __shfl_xor(vmax, 32, 64));
        float mn = fmaxf(m, vmax);
        float al = exp2f(m - mn);
        m = mn;

        float p0[4], p1[4];
        float rsum = 0.f;
#pragma unroll
        for (int r = 0; r < 4; ++r) {
            p0[r] = exp2f(s0[r] - m);
            p1[r] = exp2f(s1[r] - m);
            rsum += p0[r] + p1[r];
        }
        rsum += __shfl_xor(rsum, 16, 64);
        rsum += __shfl_xor(rsum, 32, 64);
        l = l * al + rsum;
        o0 *= al; o1 *= al; o2 *= al; o3 *= al;

        // ---- P^T redistribution: pack bf16 pairs, 8 shfl ----
        unsigned pk[4];
        pk[0] = pkbf(p0[0], p0[1]); pk[1] = pkbf(p0[2], p0[3]);
        pk[2] = pkbf(p1[0], p1[1]); pk[3] = pkbf(p1[2], p1[3]);

        union { unsigned u[4]; bf16x8 v; } pb;
#pragma unroll
        for (int t = 0; t < 4; ++t) {
            int srcl = c16 + 16 * ((2 * g + (t >> 1)) & 3);
            unsigned lo = (unsigned)__shfl((int)pk[t & 1], srcl, 64);
            unsigned hi = (unsigned)__shfl((int)pk[2 + (t & 1)], srcl, 64);
            pb.u[t] = (g < 2) ? lo : hi;
        }

        // ---- PV: O^T += V^T x P^T (V as A-operand) ----
        const __bf16* vbase = vb_ + kbase + g * 8;
        o0 = __builtin_amdgcn_mfma_f32_16x16x32_bf16(*(const bf16x8*)(vbase + (size_t)(c16) * TSEQ), pb.v, o0, 0, 0, 0);
        o1 = __builtin_amdgcn_mfma_f32_16x16x32_bf16(*(const bf16x8*)(vbase + (size_t)(c16 + 16) * TSEQ), pb.v, o1, 0, 0, 0);
        o2 = __builtin_amdgcn_mfma_f32_16x16x32_bf16(*(const bf16x8*)(vbase + (size_t)(c16 + 32) * TSEQ), pb.v, o2, 0, 0, 0);
        o3 = __builtin_amdgcn_mfma_f32_16x16x32_bf16(*(const bf16x8*)(vbase + (size_t)(c16 + 48) * TSEQ), pb.v, o3, 0, 0, 0);
    }

    // ---- publish partials ----
    ocomb[w][0][lane] = o0;
    ocomb[w][1][lane] = o1;
    ocomb[w][2][lane] = o2;
    ocomb[w][3][lane] = o3;
    if (g == 0) {
        mcomb[w][c16] = m;
        lcomb[w][c16] = l;
    }
    __syncthreads();

    // ---- combine: wave w<4 finalizes h-tile hh=w ----
    if (w < 4) {
        float M = mcomb[0][c16];
#pragma unroll
        for (int sw = 1; sw < 8; ++sw) M = fmaxf(M, mcomb[sw][c16]);
        f32x4 O = {0.f, 0.f, 0.f, 0.f};
        float L = 0.f;
#pragma unroll
        for (int sw = 0; sw < 8; ++sw) {
            float e = exp2f(mcomb[sw][c16] - M);
            L += lcomb[sw][c16] * e;
            f32x4 po = ocomb[sw][w][lane];
            O[0] += po[0] * e; O[1] += po[1] * e;
            O[2] += po[2] * e; O[3] += po[3] * e;
        }
        float rcp = 1.0f / L;
        f32x4 res = {O[0] * rcp, O[1] * rcp, O[2] * rcp, O[3] * rcp};
        *(f32x4*)(out + (size_t)(b * TSEQ + qb + c16) * HEAD + w * 16 + g * 4) = res;
    }
}

extern "C" void kernel_launch(void* const* d_in, const int* in_sizes, int n_in,
                              void* d_out, int out_size, void* d_ws, size_t ws_size,
                              hipStream_t stream) {
    const float* x  = (const float*)d_in[0];
    const float* Wk = (const float*)d_in[1];
    const float* Wq = (const float*)d_in[2];
    const float* Wv = (const float*)d_in[3];
    const float* bk = (const float*)d_in[4];
    const float* bq = (const float*)d_in[5];
    const float* bv = (const float*)d_in[6];
    float* out = (float*)d_out;

    __bf16* qs = (__bf16*)d_ws;                        // [BT][64]        1 MB
    __bf16* ks = qs + (size_t)BT * HEAD;               // [BT][64]        1 MB
    __bf16* vT = ks + (size_t)BT * HEAD;               // [NB][64][TSEQ]  1 MB
    __bf16* wt = vT + (size_t)BT * HEAD;               // [192][1024]     384 KB

    wt_kernel<<<48, 256, 0, stream>>>(Wq, Wk, Wv, wt);
    qkv_gemm<<<BT / 16, 512, 0, stream>>>(x, wt, bq, bk, bv, qs, ks, vT);
    attn_mfma<<<512, 512, 0, stream>>>(qs, ks, vT, out);
}

// Round 11
// 64.303 us; speedup vs baseline: 1.1275x; 1.0111x over previous
//
#include <hip/hip_runtime.h>
#include <hip/hip_bf16.h>

#define D_MODEL 1024
#define HEAD 64
#define TSEQ 2048
#define NB 4
#define BT (NB * TSEQ)

typedef __bf16 bf16x8 __attribute__((ext_vector_type(8)));
typedef __bf16 bf16x4 __attribute__((ext_vector_type(4)));
typedef float f32x4 __attribute__((ext_vector_type(4)));

#define LOG2E 1.44269504088896f

__device__ inline unsigned pkbf(float a, float b) {
    union { __bf16 h[2]; unsigned u; } t;
    t.h[0] = (__bf16)a; t.h[1] = (__bf16)b;
    return t.u;
}

// ---------------------------------------------------------------------------
// Kernel 0: W transpose + bf16 convert. wt[(tsel*64+col)*1024 + k] = W[k][col]
// (unchanged)
// ---------------------------------------------------------------------------
__global__ __launch_bounds__(256) void wt_kernel(
    const float* __restrict__ Wq, const float* __restrict__ Wk,
    const float* __restrict__ Wv, __bf16* __restrict__ wt)
{
    __shared__ float tile[64][65];
    int tsel = blockIdx.x >> 4;
    int k0 = (blockIdx.x & 15) * 64;
    const float* W = tsel == 0 ? Wq : (tsel == 1 ? Wk : Wv);
    int tid = threadIdx.x;
#pragma unroll
    for (int i = 0; i < 16; ++i) {
        int idx = i * 256 + tid;
        int k = idx >> 6, c = idx & 63;
        tile[k][c] = W[(size_t)(k0 + k) * 64 + c];
    }
    __syncthreads();
#pragma unroll
    for (int i = 0; i < 16; ++i) {
        int idx = i * 256 + tid;
        int c = idx >> 6, k = idx & 63;
        wt[(size_t)(tsel * 64 + c) * 1024 + k0 + k] = (__bf16)tile[k][c];
    }
}

// ---------------------------------------------------------------------------
// Kernel 1: QKV MFMA GEMM.
// ROUND 11: grid 1024 = (strip, col-half); block = 8 waves = 8-way K-split
// (K=128 per wave -> 4-iteration chain). Total work-waves 4096 -> 8192
// (32/CU nominal, ~24 resident with 48 KB LDS). XCD swizzle: XCD i owns
// strips [i*64,(i+1)*64) (its 4 MB x-slice = one L2), both col-halves.
//   d%8 = xcd; bi = d/8; strip = xcd*64 + bi/2; ch = bi&1
// Wave w covers K [w*128,(w+1)*128); cols = ch*96 + {0..95} (6 tiles).
// ---------------------------------------------------------------------------
__global__ __launch_bounds__(512) void qkv_gemm(
    const float* __restrict__ x, const __bf16* __restrict__ wt,
    const float* __restrict__ bq, const float* __restrict__ bk, const float* __restrict__ bv,
    __bf16* __restrict__ qs, __bf16* __restrict__ ks, __bf16* __restrict__ vT)
{
    __shared__ f32x4 red[8][6][64];   // 48 KB [kslice][coltile][lane]

    int d = blockIdx.x;
    int bi = d >> 3;
    int strip = (d & 7) * 64 + (bi >> 1);
    int ch = bi & 1;
    int r0 = strip * 16;

    int tid = threadIdx.x;
    int w = tid >> 6;                 // 0..7 = K slice
    int lane = tid & 63;
    int c16 = lane & 15, g = lane >> 4;

    f32x4 acc[6];
#pragma unroll
    for (int j = 0; j < 6; ++j) acc[j] = (f32x4){0.f, 0.f, 0.f, 0.f};

    const float* xbase = x + (size_t)(r0 + c16) * D_MODEL + w * 128 + g * 8;
    const __bf16* wbase = wt + (size_t)(ch * 96 + c16) * D_MODEL + w * 128 + g * 8;

    float4 xa = *(const float4*)(xbase);
    float4 xb = *(const float4*)(xbase + 4);

#pragma unroll
    for (int kt = 0; kt < 4; ++kt) {
        int k0 = kt * 32;
        float4 xa_n, xb_n;
        if (kt < 3) {                              // rolling prefetch
            xa_n = *(const float4*)(xbase + k0 + 32);
            xb_n = *(const float4*)(xbase + k0 + 36);
        }
        bf16x8 af;
        af[0] = (__bf16)xa.x; af[1] = (__bf16)xa.y;
        af[2] = (__bf16)xa.z; af[3] = (__bf16)xa.w;
        af[4] = (__bf16)xb.x; af[5] = (__bf16)xb.y;
        af[6] = (__bf16)xb.z; af[7] = (__bf16)xb.w;

        const __bf16* wk = wbase + k0;
#pragma unroll
        for (int j = 0; j < 6; ++j) {
            bf16x8 bfr = *(const bf16x8*)(wk + (size_t)j * 16 * D_MODEL);
            acc[j] = __builtin_amdgcn_mfma_f32_16x16x32_bf16(af, bfr, acc[j], 0, 0, 0);
        }
        xa = xa_n; xb = xb_n;
    }

#pragma unroll
    for (int j = 0; j < 6; ++j) red[w][j][lane] = acc[j];
    __syncthreads();

    // waves 0-5 finalize col-tile j=w: sum 8 K-slice partials
    if (w < 6) {
        int j = w;
        f32x4 s = red[0][j][lane];
#pragma unroll
        for (int sw = 1; sw < 8; ++sw) s += red[sw][j][lane];

        int col = ch * 96 + j * 16 + c16;   // global column 0..191
        int tsel = col >> 6;                // 0=q 1=k 2=v
        int cm = col & 63;                  // column within its matrix
        const float* bias = tsel == 0 ? bq : (tsel == 1 ? bk : bv);
        float bval = bias[cm];
        if (tsel == 0) {
            // q pre-scaled by 1/sqrt(1024) * log2(e) so attn can use exp2
#pragma unroll
            for (int r = 0; r < 4; ++r)
                qs[(size_t)(r0 + g * 4 + r) * HEAD + cm] = (__bf16)((s[r] + bval) * (0.03125f * LOG2E));
        } else if (tsel == 1) {
#pragma unroll
            for (int r = 0; r < 4; ++r)
                ks[(size_t)(r0 + g * 4 + r) * HEAD + cm] = (__bf16)(s[r] + bval);
        } else {
#pragma unroll
            for (int r = 0; r < 4; ++r) {
                int row = r0 + g * 4 + r;
                int b = row >> 11, t = row & (TSEQ - 1);
                vT[(size_t)(b * HEAD + cm) * TSEQ + t] = (__bf16)(s[r] + bval);
            }
        }
    }
}

// ---------------------------------------------------------------------------
// Kernel 2: flash attention, 8-way key-split, swapped QK^T + XCD swizzle
// (unchanged from round 10).
// ---------------------------------------------------------------------------
__global__ __launch_bounds__(512) void attn_mfma(
    const __bf16* __restrict__ qs, const __bf16* __restrict__ ks,
    const __bf16* __restrict__ vT, float* __restrict__ out)
{
    __shared__ __align__(16) f32x4 ocomb[8][4][64];     // 32 KB [wave][hh][lane]
    __shared__ float mcomb[8][16];                      // [wave][qrow]
    __shared__ float lcomb[8][16];

    int d = blockIdx.x;
    int xcd = d & 7;
    int slot = d >> 3;                  // 0..63
    int b = xcd >> 1;
    int qt = ((xcd & 1) ? 127 : 126) - 2 * slot;   // heavy-first, parity split
    int qb = qt * 16;

    int tid = threadIdx.x;
    int w = tid >> 6;                   // 0..7
    int lane = tid & 63;
    int g = lane >> 4;
    int c16 = lane & 15;

    const __bf16* qsb = qs + (size_t)(b * TSEQ + qb) * HEAD;
    const __bf16* kb_ = ks + (size_t)b * TSEQ * HEAD;
    const __bf16* vb_ = vT + (size_t)b * HEAD * TSEQ;

    bf16x8 qf0 = *(const bf16x8*)(qsb + c16 * HEAD + g * 8);
    bf16x8 qf1 = *(const bf16x8*)(qsb + c16 * HEAD + 32 + g * 8);

    f32x4 o0 = {0.f, 0.f, 0.f, 0.f}, o1 = o0, o2 = o0, o3 = o0;
    float m = -3.0e38f, l = 0.f;

    int nt = (qb + 47) >> 5;            // number of 32-key tiles
    int qrow = qb + c16;

    for (int ti = w; ti < nt; ti += 8) {
        int kbase = ti * 32;

        // ---- QK^T (swapped: K as A, Q as B -> S^T) ----
        const __bf16* kr0 = kb_ + (size_t)(kbase + c16) * HEAD + g * 8;
        bf16x8 k00 = *(const bf16x8*)(kr0);
        bf16x8 k01 = *(const bf16x8*)(kr0 + 32);
        const __bf16* kr1 = kr0 + 16 * HEAD;
        bf16x8 k10 = *(const bf16x8*)(kr1);
        bf16x8 k11 = *(const bf16x8*)(kr1 + 32);

        f32x4 z = {0.f, 0.f, 0.f, 0.f};
        f32x4 s0 = __builtin_amdgcn_mfma_f32_16x16x32_bf16(k00, qf0, z, 0, 0, 0);
        s0 = __builtin_amdgcn_mfma_f32_16x16x32_bf16(k01, qf1, s0, 0, 0, 0);
        f32x4 s1 = __builtin_amdgcn_mfma_f32_16x16x32_bf16(k10, qf0, z, 0, 0, 0);
        s1 = __builtin_amdgcn_mfma_f32_16x16x32_bf16(k11, qf1, s1, 0, 0, 0);

        // ---- causal mask (keys are in-lane) ----
        if (kbase + 31 > qb) {
#pragma unroll
            for (int r = 0; r < 4; ++r) {
                if (kbase + 4 * g + r > qrow)      s0[r] = -3.0e38f;
                if (kbase + 16 + 4 * g + r > qrow) s1[r] = -3.0e38f;
            }
        }

        // ---- online softmax: lane-local row ----
        float vmax = fmaxf(fmaxf(fmaxf(s0[0], s0[1]), fmaxf(s0[2], s0[3])),
                           fmaxf(fmaxf(s1[0], s1[1]), fmaxf(s1[2], s1[3])));
        vmax = fmaxf(vmax, __shfl_xor(vmax, 16, 64));
        vmax = fmaxf(vmax, __shfl_xor(vmax, 32, 64));
        float mn = fmaxf(m, vmax);
        float al = exp2f(m - mn);
        m = mn;

        float p0[4], p1[4];
        float rsum = 0.f;
#pragma unroll
        for (int r = 0; r < 4; ++r) {
            p0[r] = exp2f(s0[r] - m);
            p1[r] = exp2f(s1[r] - m);
            rsum += p0[r] + p1[r];
        }
        rsum += __shfl_xor(rsum, 16, 64);
        rsum += __shfl_xor(rsum, 32, 64);
        l = l * al + rsum;
        o0 *= al; o1 *= al; o2 *= al; o3 *= al;

        // ---- P^T redistribution: pack bf16 pairs, 8 shfl ----
        unsigned pk[4];
        pk[0] = pkbf(p0[0], p0[1]); pk[1] = pkbf(p0[2], p0[3]);
        pk[2] = pkbf(p1[0], p1[1]); pk[3] = pkbf(p1[2], p1[3]);

        union { unsigned u[4]; bf16x8 v; } pb;
#pragma unroll
        for (int t = 0; t < 4; ++t) {
            int srcl = c16 + 16 * ((2 * g + (t >> 1)) & 3);
            unsigned lo = (unsigned)__shfl((int)pk[t & 1], srcl, 64);
            unsigned hi = (unsigned)__shfl((int)pk[2 + (t & 1)], srcl, 64);
            pb.u[t] = (g < 2) ? lo : hi;
        }

        // ---- PV: O^T += V^T x P^T (V as A-operand) ----
        const __bf16* vbase = vb_ + kbase + g * 8;
        o0 = __builtin_amdgcn_mfma_f32_16x16x32_bf16(*(const bf16x8*)(vbase + (size_t)(c16) * TSEQ), pb.v, o0, 0, 0, 0);
        o1 = __builtin_amdgcn_mfma_f32_16x16x32_bf16(*(const bf16x8*)(vbase + (size_t)(c16 + 16) * TSEQ), pb.v, o1, 0, 0, 0);
        o2 = __builtin_amdgcn_mfma_f32_16x16x32_bf16(*(const bf16x8*)(vbase + (size_t)(c16 + 32) * TSEQ), pb.v, o2, 0, 0, 0);
        o3 = __builtin_amdgcn_mfma_f32_16x16x32_bf16(*(const bf16x8*)(vbase + (size_t)(c16 + 48) * TSEQ), pb.v, o3, 0, 0, 0);
    }

    // ---- publish partials ----
    ocomb[w][0][lane] = o0;
    ocomb[w][1][lane] = o1;
    ocomb[w][2][lane] = o2;
    ocomb[w][3][lane] = o3;
    if (g == 0) {
        mcomb[w][c16] = m;
        lcomb[w][c16] = l;
    }
    __syncthreads();

    // ---- combine: wave w<4 finalizes h-tile hh=w ----
    if (w < 4) {
        float M = mcomb[0][c16];
#pragma unroll
        for (int sw = 1; sw < 8; ++sw) M = fmaxf(M, mcomb[sw][c16]);
        f32x4 O = {0.f, 0.f, 0.f, 0.f};
        float L = 0.f;
#pragma unroll
        for (int sw = 0; sw < 8; ++sw) {
            float e = exp2f(mcomb[sw][c16] - M);
            L += lcomb[sw][c16] * e;
            f32x4 po = ocomb[sw][w][lane];
            O[0] += po[0] * e; O[1] += po[1] * e;
            O[2] += po[2] * e; O[3] += po[3] * e;
        }
        float rcp = 1.0f / L;
        f32x4 res = {O[0] * rcp, O[1] * rcp, O[2] * rcp, O[3] * rcp};
        *(f32x4*)(out + (size_t)(b * TSEQ + qb + c16) * HEAD + w * 16 + g * 4) = res;
    }
}

extern "C" void kernel_launch(void* const* d_in, const int* in_sizes, int n_in,
                              void* d_out, int out_size, void* d_ws, size_t ws_size,
                              hipStream_t stream) {
    const float* x  = (const float*)d_in[0];
    const float* Wk = (const float*)d_in[1];
    const float* Wq = (const float*)d_in[2];
    const float* Wv = (const float*)d_in[3];
    const float* bk = (const float*)d_in[4];
    const float* bq = (const float*)d_in[5];
    const float* bv = (const float*)d_in[6];
    float* out = (float*)d_out;

    __bf16* qs = (__bf16*)d_ws;                        // [BT][64]        1 MB
    __bf16* ks = qs + (size_t)BT * HEAD;               // [BT][64]        1 MB
    __bf16* vT = ks + (size_t)BT * HEAD;               // [NB][64][TSEQ]  1 MB
    __bf16* wt = vT + (size_t)BT * HEAD;               // [192][1024]     384 KB

    wt_kernel<<<48, 256, 0, stream>>>(Wq, Wk, Wv, wt);
    qkv_gemm<<<1024, 512, 0, stream>>>(x, wt, bq, bk, bv, qs, ks, vT);
    attn_mfma<<<512, 512, 0, stream>>>(qs, ks, vT, out);
}